// Round 5
// baseline (35.863 us; speedup 1.0000x reference)
//
#include <hip/hip_runtime.h>
#include <stdint.h>
#include <stddef.h>

// Problem constants
#define D_FEAT 1280
#define N_PAD  256
#define N_OUT  248
#define BM     64
#define BK     64
#define K_ITERS 20
#define W_TILE_BYTES (N_PAD * BK * 2)   // 32 KB bf16 weight tile

typedef float f32x4 __attribute__((ext_vector_type(4)));
typedef short s16x8 __attribute__((ext_vector_type(8)));
typedef unsigned int u32x4 __attribute__((ext_vector_type(4)));

__device__ __forceinline__ unsigned short f2bf(float f) {
  union { float f; unsigned int u; } v; v.f = f;
  unsigned int r = (v.u + 0x7fffu + ((v.u >> 16) & 1u)) >> 16;
  return (unsigned short)r;
}

// one v_cvt_pk_bf16_f32: packs 2 fp32 -> 2 bf16 (RTNE), lo=a, hi=b
__device__ __forceinline__ unsigned int cvt_pk(float a, float b) {
  unsigned int r;
  asm("v_cvt_pk_bf16_f32 %0, %1, %2" : "=v"(r) : "v"(a), "v"(b));
  return r;
}

__device__ __forceinline__ void gload16(const void* g, void* l) {
  __builtin_amdgcn_global_load_lds(
      (const __attribute__((address_space(1))) void*)g,
      (__attribute__((address_space(3))) void*)l, 16, 0, 0);
}

// ---------------------------------------------------------------------------
// Pack W_final (D,8), Wp1 (8,D,6), Wp2 (8,6,D,4) into one bf16 matrix laid out
// exactly as the main kernel's LDS B-tiles expect (XOR swizzle pre-baked so
// global_load_lds is a LINEAR copy and ds_read_b128 is conflict-free).
// Tile kt: [n=0..255][s_phys=0..7] 16B chunks; chunk(n,s_phys) holds
// W[n][kt*64 + 8*(s_phys ^ (n&7)) .. +7].
// ---------------------------------------------------------------------------
__global__ __launch_bounds__(256) void pack_w_kernel(
    const float* __restrict__ Wf, const float* __restrict__ Wp1,
    const float* __restrict__ Wp2, unsigned short* __restrict__ out) {
  int idx = blockIdx.x * 256 + threadIdx.x;    // 0 .. 327679
  int e = idx & 7;
  int chunk = idx >> 3;
  int s_phys = chunk & 7;
  int n = (chunk >> 3) & 255;
  int kt = chunk >> 11;
  int s_log = s_phys ^ (n & 7);
  int d = kt * BK + s_log * 8 + e;
  float v = 0.0f;
  if (n < 8) {
    v = Wf[d * 8 + n];
  } else if (n < 56) {
    int m = n - 8;
    v = Wp1[((m / 6) * D_FEAT + d) * 6 + (m % 6)];
  } else if (n < 248) {
    int m = n - 56;
    v = Wp2[(((m / 24) * 6 + ((m % 24) >> 2)) * D_FEAT + d) * 4 + (m & 3)];
  }
  out[idx] = f2bf(v);
}

// ---------------------------------------------------------------------------
// Fused GEMM (bf16 MFMA) + hierarchical softmax epilogue.
// 512 threads = 8 waves (2M x 4N): wave tile = 32 rows x 64 cols.
// A: plain global loads -> regs (issued one iter early), cvt_pk to bf16 ONCE,
//    ds_write_b128 into LDS[row][slot^(row&7)] (bandwidth-minimal layout).
// B: bf16, pre-swizzled in global by pack_w_kernel, staged via global_load_lds.
// Pipeline: 2-deep, 3 buffers (A 8KB + B 32KB each, 120KB), branch-free
// counted s_waitcnt vmcnt(6) (4 B-gloads + 2 A-loads per wave per tile),
// raw s_barrier preceded only by lgkmcnt(0). Fully unrolled, no branches.
// ---------------------------------------------------------------------------
__global__ __launch_bounds__(512, 2) void tree_head_kernel(
    const float* __restrict__ x, const unsigned short* __restrict__ Wb,
    const float* __restrict__ b_final, const float* __restrict__ wu1,
    const float* __restrict__ b1, const float* __restrict__ wu2,
    const float* __restrict__ b2, float* __restrict__ out) {
  __shared__ __align__(16) char smem[122880];  // 3x8KB A(bf16) + 3x32KB B
  char* A0 = smem;
  char* A1 = smem + 8192;
  char* A2 = smem + 16384;
  char* B0 = smem + 24576;
  char* B1 = smem + 57344;
  char* B2 = smem + 90112;

  const int tid  = threadIdx.x;
  const int lane = tid & 63;
  const int wave = tid >> 6;       // 0..7
  const int wm   = wave >> 2;      // 0..1 (M half)
  const int wn   = wave & 3;       // 0..3 (N quarter)
  const int l15  = lane & 15;
  const int lh   = lane >> 4;      // 0..3
  const int row0 = blockIdx.x * BM;

  f32x4 acc[2][4];
#pragma unroll
  for (int m = 0; m < 2; ++m)
#pragma unroll
    for (int n = 0; n < 4; ++n)
#pragma unroll
      for (int j = 0; j < 4; ++j) acc[m][n][j] = 0.0f;

  // A staging: thread t owns row=t>>3, slot=t&7 (8 k's = 32B fp32 -> 16B bf16)
  const int arow = tid >> 3;
  const int aslot = tid & 7;
  const char* aptr = (const char*)x + ((size_t)(row0 + arow) * D_FEAT + aslot * 8) * 4;
  const int awoff = arow * 128 + ((aslot ^ (arow & 7)) << 4);
  // B staging: 4 gload_lds per thread; linear copy of pre-swizzled tile
  const char* bsrc = (const char*)Wb + wave * 1024 + lane * 16;
  const int bdst = wave * 1024;

  f32x4 ra[3][2];   // A fp32 prefetch regs, 3-phase rotation (static indices)

#define STAGEB(kt_, dB_) do {                                                 \
    _Pragma("unroll")                                                         \
    for (int j_ = 0; j_ < 4; ++j_)                                            \
      gload16(bsrc + (size_t)(kt_) * W_TILE_BYTES + j_ * 8192,                \
              (dB_) + bdst + j_ * 8192);                                      \
  } while (0)

#define LOADA(kt_, ri_) do {                                                  \
    ra[ri_][0] = *(const f32x4*)(aptr + (kt_) * 256);                         \
    ra[ri_][1] = *(const f32x4*)(aptr + (kt_) * 256 + 16);                    \
  } while (0)

#define WRITEA(ri_, dA_) do {                                                 \
    union { u32x4 u; s16x8 s; } pk_;                                          \
    pk_.u[0] = cvt_pk(ra[ri_][0][0], ra[ri_][0][1]);                          \
    pk_.u[1] = cvt_pk(ra[ri_][0][2], ra[ri_][0][3]);                          \
    pk_.u[2] = cvt_pk(ra[ri_][1][0], ra[ri_][1][1]);                          \
    pk_.u[3] = cvt_pk(ra[ri_][1][2], ra[ri_][1][3]);                          \
    *(s16x8*)((dA_) + awoff) = pk_.s;                                         \
  } while (0)

#define COMPUTE(cA_, cB_) do {                                                \
    s16x8 fr[2][2];                                                           \
    _Pragma("unroll")                                                         \
    for (int m_ = 0; m_ < 2; ++m_) {                                          \
      int rl_ = wm * 32 + m_ * 16 + l15;                                      \
      _Pragma("unroll")                                                       \
      for (int ks_ = 0; ks_ < 2; ++ks_) {                                     \
        int sl_ = ks_ * 4 + lh;                                               \
        fr[m_][ks_] = *(const s16x8*)((cA_) + rl_ * 128 +                     \
                                      ((sl_ ^ (rl_ & 7)) << 4));              \
      }                                                                       \
    }                                                                         \
    _Pragma("unroll")                                                         \
    for (int ks_ = 0; ks_ < 2; ++ks_) {                                       \
      int sl_ = ks_ * 4 + lh;                                                 \
      _Pragma("unroll")                                                       \
      for (int nf_ = 0; nf_ < 4; ++nf_) {                                     \
        int n_ = wn * 64 + nf_ * 16 + l15;                                    \
        s16x8 b_ = *(const s16x8*)((cB_) + n_ * 128 + ((sl_ ^ (n_ & 7)) << 4));\
        acc[0][nf_] = __builtin_amdgcn_mfma_f32_16x16x32_bf16(fr[0][ks_], b_, acc[0][nf_], 0, 0, 0); \
        acc[1][nf_] = __builtin_amdgcn_mfma_f32_16x16x32_bf16(fr[1][ks_], b_, acc[1][nf_], 0, 0, 0); \
      }                                                                       \
    }                                                                         \
  } while (0)

  // ITER(kt): [lgkm+barrier] [stage kt+2: 4 B-gloads + 2 A-loads] [vmcnt(6):
  // batch kt+1 landed] [cvt+write A(kt+1)] [compute kt]
#define ITER(kt_, cA_, cB_, wA_, sB_, rl_, rc_) do {                          \
    asm volatile("s_waitcnt lgkmcnt(0)" ::: "memory");                        \
    __builtin_amdgcn_sched_barrier(0);                                        \
    __builtin_amdgcn_s_barrier();                                             \
    __builtin_amdgcn_sched_barrier(0);                                        \
    STAGEB((kt_) + 2, sB_);                                                   \
    LOADA((kt_) + 2, rl_);                                                    \
    __builtin_amdgcn_sched_barrier(0);                                        \
    asm volatile("s_waitcnt vmcnt(6)" ::: "memory");                          \
    __builtin_amdgcn_sched_barrier(0);                                        \
    WRITEA(rc_, wA_);                                                         \
    COMPUTE(cA_, cB_);                                                        \
  } while (0)

  // ---- prologue: stage batches 0 and 1; convert+write A(0) ----------------
  STAGEB(0, B0);
  LOADA(0, 0);
  STAGEB(1, B1);
  LOADA(1, 1);
  __builtin_amdgcn_sched_barrier(0);
  asm volatile("s_waitcnt vmcnt(6)" ::: "memory");   // batch 0 landed
  __builtin_amdgcn_sched_barrier(0);
  WRITEA(0, A0);

  // ---- main loop: kt = 0..17, 3-phase buffer/reg rotation ----------------
  for (int t = 0; t < 6; ++t) {
    ITER(3 * t + 0, A0, B0, A1, B2, 2, 1);
    ITER(3 * t + 1, A1, B1, A2, B0, 0, 2);
    ITER(3 * t + 2, A2, B2, A0, B1, 1, 0);
  }

  // ---- tails: kt = 18 (write A19), kt = 19 --------------------------------
  asm volatile("s_waitcnt lgkmcnt(0)" ::: "memory");
  __builtin_amdgcn_sched_barrier(0);
  __builtin_amdgcn_s_barrier();
  __builtin_amdgcn_sched_barrier(0);
  asm volatile("s_waitcnt vmcnt(0)" ::: "memory");   // batch 19 landed
  __builtin_amdgcn_sched_barrier(0);
  WRITEA(1, A1);
  COMPUTE(A0, B0);

  asm volatile("s_waitcnt lgkmcnt(0)" ::: "memory");
  __builtin_amdgcn_sched_barrier(0);
  __builtin_amdgcn_s_barrier();
  __builtin_amdgcn_sched_barrier(0);
  COMPUTE(A1, B1);

  __syncthreads();   // full drain before smem reuse as Ls

  // ---- epilogue: logits -> LDS, column-major stride 65 --------------------
  float* Ls = (float*)smem;            // Ls[col*65 + row], col<248 (64.5 KB)
#pragma unroll
  for (int m = 0; m < 2; ++m)
#pragma unroll
    for (int nf = 0; nf < 4; ++nf) {
      int col = wn * 64 + nf * 16 + l15;
      if (col < N_OUT) {
        int rbase = wm * 32 + m * 16 + (lh << 2);
#pragma unroll
        for (int i = 0; i < 4; ++i) Ls[col * 65 + rbase + i] = acc[m][nf][i];
      }
    }
  __syncthreads();

  // 8 threads per row: part p owns root i=p entirely (u1, level-1, level-2).
  const int p = tid & 7;
  const int r = tid >> 3;              // 0..63
  float* orow = out + (size_t)(row0 + r) * N_OUT;

  float ui = Ls[p * 65 + r] + b_final[p];
  orow[p] = ui;

  // level-1: softmax over 6, then u2 = p1 * u1
  float lg[6];
  float mx = -1e30f;
#pragma unroll
  for (int c = 0; c < 6; ++c) {
    lg[c] = Ls[(8 + p * 6 + c) * 65 + r] + ui * wu1[p * 6 + c] + b1[p * 6 + c];
    mx = fmaxf(mx, lg[c]);
  }
  float s = 0.0f;
#pragma unroll
  for (int c = 0; c < 6; ++c) { lg[c] = __expf(lg[c] - mx); s += lg[c]; }
  float sc = ui / s;
  float u2v[6];
#pragma unroll
  for (int c = 0; c < 6; ++c) {
    u2v[c] = lg[c] * sc;
    orow[8 + p * 6 + c] = u2v[c];
  }

  // level-2: 6 groups of 4, u3 = p2 * u2
#pragma unroll
  for (int j = 0; j < 6; ++j) {
    int g = p * 6 + j;
    float ug = u2v[j];
    float l2[4];
    float m2 = -1e30f;
#pragma unroll
    for (int c = 0; c < 4; ++c) {
      l2[c] = Ls[(56 + g * 4 + c) * 65 + r] + ug * wu2[g * 4 + c] + b2[g * 4 + c];
      m2 = fmaxf(m2, l2[c]);
    }
    float s2 = 0.0f;
#pragma unroll
    for (int c = 0; c < 4; ++c) { l2[c] = __expf(l2[c] - m2); s2 += l2[c]; }
    float sc2 = ug / s2;
    f32x4 o;
#pragma unroll
    for (int c = 0; c < 4; ++c) o[c] = l2[c] * sc2;
    *(f32x4*)(orow + 56 + g * 4) = o;
  }
#undef STAGEB
#undef LOADA
#undef WRITEA
#undef COMPUTE
#undef ITER
}

// ---------------------------------------------------------------------------
extern "C" void kernel_launch(void* const* d_in, const int* in_sizes, int n_in,
                              void* d_out, int out_size, void* d_ws, size_t ws_size,
                              hipStream_t stream) {
  const float* x   = (const float*)d_in[0];
  const float* Wf  = (const float*)d_in[1];
  const float* bf  = (const float*)d_in[2];
  const float* Wp1 = (const float*)d_in[3];
  const float* wu1 = (const float*)d_in[4];
  const float* b1  = (const float*)d_in[5];
  const float* Wp2 = (const float*)d_in[6];
  const float* wu2 = (const float*)d_in[7];
  const float* b2  = (const float*)d_in[8];
  float* out = (float*)d_out;
  unsigned short* Wb = (unsigned short*)d_ws;   // 655,360 B packed bf16 weights

  pack_w_kernel<<<1280, 256, 0, stream>>>(Wf, Wp1, Wp2, Wb);
  tree_head_kernel<<<16384 / BM, 512, 0, stream>>>(x, Wb, bf, wu1, b1, wu2, b2, out);
}

// Round 6
// 34.982 us; speedup vs baseline: 1.0252x; 1.0252x over previous
//
#include <hip/hip_runtime.h>
#include <stdint.h>
#include <stddef.h>

// Problem constants
#define D_FEAT 1280
#define N_PAD  256
#define N_OUT  248
#define BM     64
#define BK     64
#define K_ITERS 20
#define W_TILE_BYTES (N_PAD * BK * 2)   // 32 KB bf16 weight tile

typedef float f32x4 __attribute__((ext_vector_type(4)));
typedef short s16x8 __attribute__((ext_vector_type(8)));
typedef unsigned int u32x4 __attribute__((ext_vector_type(4)));

__device__ __forceinline__ unsigned short f2bf(float f) {
  union { float f; unsigned int u; } v; v.f = f;
  unsigned int r = (v.u + 0x7fffu + ((v.u >> 16) & 1u)) >> 16;
  return (unsigned short)r;
}

// one v_cvt_pk_bf16_f32: packs 2 fp32 -> 2 bf16 (RTNE), lo=a, hi=b
__device__ __forceinline__ unsigned int cvt_pk(float a, float b) {
  unsigned int r;
  asm("v_cvt_pk_bf16_f32 %0, %1, %2" : "=v"(r) : "v"(a), "v"(b));
  return r;
}

__device__ __forceinline__ void gload16(const void* g, void* l) {
  __builtin_amdgcn_global_load_lds(
      (const __attribute__((address_space(1))) void*)g,
      (__attribute__((address_space(3))) void*)l, 16, 0, 0);
}

// ---------------------------------------------------------------------------
// Pack W_final (D,8), Wp1 (8,D,6), Wp2 (8,6,D,4) into one bf16 matrix laid out
// exactly as the main kernel's LDS B-tiles expect (XOR swizzle pre-baked so
// global_load_lds is a LINEAR copy and ds_read_b128 is conflict-free).
// Tile kt: [n=0..255][s_phys=0..7] 16B chunks; chunk(n,s_phys) holds
// W[n][kt*64 + 8*(s_phys ^ (n&7)) .. +7].
// Vectorized: one thread = one 16B chunk (8 bf16) -> 40960 threads.
// ---------------------------------------------------------------------------
__global__ __launch_bounds__(256) void pack_w_kernel(
    const float* __restrict__ Wf, const float* __restrict__ Wp1,
    const float* __restrict__ Wp2, unsigned short* __restrict__ out) {
  int chunk = blockIdx.x * 256 + threadIdx.x;    // 0 .. 40959
  int s_phys = chunk & 7;
  int n = (chunk >> 3) & 255;
  int kt = chunk >> 11;
  int s_log = s_phys ^ (n & 7);
  int d0 = kt * BK + s_log * 8;
  float v[8];
#pragma unroll
  for (int e = 0; e < 8; ++e) v[e] = 0.0f;
  if (n < 8) {
#pragma unroll
    for (int e = 0; e < 8; ++e) v[e] = Wf[(d0 + e) * 8 + n];
  } else if (n < 56) {
    int m = n - 8;
    const float* base = Wp1 + (size_t)(m / 6) * D_FEAT * 6 + (m % 6);
#pragma unroll
    for (int e = 0; e < 8; ++e) v[e] = base[(d0 + e) * 6];
  } else if (n < 248) {
    int m = n - 56;
    const float* base = Wp2 + ((size_t)(m / 24) * 6 + ((m % 24) >> 2)) * D_FEAT * 4 + (m & 3);
#pragma unroll
    for (int e = 0; e < 8; ++e) v[e] = base[(d0 + e) * 4];
  }
  union { u32x4 u; s16x8 s; } pk;
#pragma unroll
  for (int h = 0; h < 4; ++h) pk.u[h] = cvt_pk(v[2 * h], v[2 * h + 1]);
  *(s16x8*)(out + (size_t)chunk * 8) = pk.s;
}

// ---------------------------------------------------------------------------
// Fused GEMM (bf16 MFMA) + hierarchical softmax epilogue.
// 512 threads = 8 waves (2M x 4N): wave tile = 32 rows x 64 cols.
// A: plain global loads -> regs THREE tiles ahead (2-iter flight vs HBM
//    latency), cvt_pk to bf16 once, ds_write into LDS[row][slot^(row&7)].
// B: bf16 pre-swizzled in global, staged via global_load_lds (L2-resident,
//    1-iter flight). Branch-free VMEM queue: 6 issues/iter, steady
//    outstanding 8 -> s_waitcnt vmcnt(8) retires exactly A(kt+1)+B(kt+1).
// Raw s_barrier preceded only by lgkmcnt(0). Fully unrolled, no branches.
// ---------------------------------------------------------------------------
__global__ __launch_bounds__(512, 2) void tree_head_kernel(
    const float* __restrict__ x, const unsigned short* __restrict__ Wb,
    const float* __restrict__ b_final, const float* __restrict__ wu1,
    const float* __restrict__ b1, const float* __restrict__ wu2,
    const float* __restrict__ b2, float* __restrict__ out) {
  __shared__ __align__(16) char smem[122880];  // 3x8KB A(bf16) + 3x32KB B
  char* A0 = smem;
  char* A1 = smem + 8192;
  char* A2 = smem + 16384;
  char* B0 = smem + 24576;
  char* B1 = smem + 57344;
  char* B2 = smem + 90112;

  const int tid  = threadIdx.x;
  const int lane = tid & 63;
  const int wave = tid >> 6;       // 0..7
  const int wm   = wave >> 2;      // 0..1 (M half)
  const int wn   = wave & 3;       // 0..3 (N quarter)
  const int l15  = lane & 15;
  const int lh   = lane >> 4;      // 0..3
  const int row0 = blockIdx.x * BM;

  f32x4 acc[2][4];
#pragma unroll
  for (int m = 0; m < 2; ++m)
#pragma unroll
    for (int n = 0; n < 4; ++n)
#pragma unroll
      for (int j = 0; j < 4; ++j) acc[m][n][j] = 0.0f;

  // A staging: thread t owns row=t>>3, slot=t&7 (8 k's = 32B fp32 -> 16B bf16)
  const int arow = tid >> 3;
  const int aslot = tid & 7;
  const char* aptr = (const char*)x + ((size_t)(row0 + arow) * D_FEAT + aslot * 8) * 4;
  const int awoff = arow * 128 + ((aslot ^ (arow & 7)) << 4);
  // B staging: 4 gload_lds per thread; linear copy of pre-swizzled tile
  const char* bsrc = (const char*)Wb + wave * 1024 + lane * 16;
  const int bdst = wave * 1024;

  f32x4 ra[3][2];   // A fp32 prefetch regs, 3-slot rotation (static indices)

#define STAGEB(kt_, dB_) do {                                                 \
    _Pragma("unroll")                                                         \
    for (int j_ = 0; j_ < 4; ++j_)                                            \
      gload16(bsrc + (size_t)(kt_) * W_TILE_BYTES + j_ * 8192,                \
              (dB_) + bdst + j_ * 8192);                                      \
  } while (0)

#define LOADA(kt_, ri_) do {                                                  \
    ra[ri_][0] = *(const f32x4*)(aptr + (kt_) * 256);                         \
    ra[ri_][1] = *(const f32x4*)(aptr + (kt_) * 256 + 16);                    \
  } while (0)

#define WRITEA(ri_, dA_) do {                                                 \
    union { u32x4 u; s16x8 s; } pk_;                                          \
    pk_.u[0] = cvt_pk(ra[ri_][0][0], ra[ri_][0][1]);                          \
    pk_.u[1] = cvt_pk(ra[ri_][0][2], ra[ri_][0][3]);                          \
    pk_.u[2] = cvt_pk(ra[ri_][1][0], ra[ri_][1][1]);                          \
    pk_.u[3] = cvt_pk(ra[ri_][1][2], ra[ri_][1][3]);                          \
    *(s16x8*)((dA_) + awoff) = pk_.s;                                         \
  } while (0)

#define COMPUTE(cA_, cB_) do {                                                \
    s16x8 fr[2][2];                                                           \
    _Pragma("unroll")                                                         \
    for (int m_ = 0; m_ < 2; ++m_) {                                          \
      int rl_ = wm * 32 + m_ * 16 + l15;                                      \
      _Pragma("unroll")                                                       \
      for (int ks_ = 0; ks_ < 2; ++ks_) {                                     \
        int sl_ = ks_ * 4 + lh;                                               \
        fr[m_][ks_] = *(const s16x8*)((cA_) + rl_ * 128 +                     \
                                      ((sl_ ^ (rl_ & 7)) << 4));              \
      }                                                                       \
    }                                                                         \
    _Pragma("unroll")                                                         \
    for (int ks_ = 0; ks_ < 2; ++ks_) {                                       \
      int sl_ = ks_ * 4 + lh;                                                 \
      _Pragma("unroll")                                                       \
      for (int nf_ = 0; nf_ < 4; ++nf_) {                                     \
        int n_ = wn * 64 + nf_ * 16 + l15;                                    \
        s16x8 b_ = *(const s16x8*)((cB_) + n_ * 128 + ((sl_ ^ (n_ & 7)) << 4));\
        acc[0][nf_] = __builtin_amdgcn_mfma_f32_16x16x32_bf16(fr[0][ks_], b_, acc[0][nf_], 0, 0, 0); \
        acc[1][nf_] = __builtin_amdgcn_mfma_f32_16x16x32_bf16(fr[1][ks_], b_, acc[1][nf_], 0, 0, 0); \
      }                                                                       \
    }                                                                         \
  } while (0)

  // ITER(kt): [lgkm+barrier] [stage B(kt+2): 4 gloads; load A(kt+3): 2 loads]
  // [vmcnt(8): retires A(kt+1)+B(kt+1)] [cvt+write A(kt+1)] [compute kt]
#define ITER(kt_, cA_, cB_, wA_, sB_, ls_, ws_) do {                          \
    asm volatile("s_waitcnt lgkmcnt(0)" ::: "memory");                        \
    __builtin_amdgcn_sched_barrier(0);                                        \
    __builtin_amdgcn_s_barrier();                                             \
    __builtin_amdgcn_sched_barrier(0);                                        \
    STAGEB((kt_) + 2, sB_);                                                   \
    LOADA((kt_) + 3, ls_);                                                    \
    __builtin_amdgcn_sched_barrier(0);                                        \
    asm volatile("s_waitcnt vmcnt(8)" ::: "memory");                          \
    __builtin_amdgcn_sched_barrier(0);                                        \
    WRITEA(ws_, wA_);                                                         \
    COMPUTE(cA_, cB_);                                                        \
  } while (0)

  // ---- prologue: queue = [B0:4, A0:2, A1:2, B1:4, A2:2] = 14 --------------
  STAGEB(0, B0);
  LOADA(0, 0);
  LOADA(1, 1);
  STAGEB(1, B1);
  LOADA(2, 2);
  __builtin_amdgcn_sched_barrier(0);
  asm volatile("s_waitcnt vmcnt(8)" ::: "memory");   // retires B0 + A0
  __builtin_amdgcn_sched_barrier(0);
  WRITEA(0, A0);
  // steady-state entering kt=0: [A1:2, B1:4, A2:2] = 8 outstanding

  // ---- main loop: kt = 0..16 (buffers/slots rotate mod 3) -----------------
  for (int t = 0; t < 5; ++t) {
    ITER(3 * t + 0, A0, B0, A1, B2, 0, 1);
    ITER(3 * t + 1, A1, B1, A2, B0, 1, 2);
    ITER(3 * t + 2, A2, B2, A0, B1, 2, 0);
  }
  ITER(15, A0, B0, A1, B2, 0, 1);
  ITER(16, A1, B1, A2, B0, 1, 2);

  // ---- tails ----------------------------------------------------------------
  // kt=17: stage B(19) only; queue [A18:2,B18:4,A19:2]+[B19:4]=12; vmcnt(6)
  asm volatile("s_waitcnt lgkmcnt(0)" ::: "memory");
  __builtin_amdgcn_sched_barrier(0);
  __builtin_amdgcn_s_barrier();
  __builtin_amdgcn_sched_barrier(0);
  STAGEB(19, B1);
  __builtin_amdgcn_sched_barrier(0);
  asm volatile("s_waitcnt vmcnt(6)" ::: "memory");   // retires A18 + B18
  __builtin_amdgcn_sched_barrier(0);
  WRITEA(0, A0);                                     // A(18) -> A0
  COMPUTE(A2, B2);                                   // tile 17

  // kt=18: queue [A19:2, B19:4]; vmcnt(0)
  asm volatile("s_waitcnt lgkmcnt(0)" ::: "memory");
  __builtin_amdgcn_sched_barrier(0);
  __builtin_amdgcn_s_barrier();
  __builtin_amdgcn_sched_barrier(0);
  asm volatile("s_waitcnt vmcnt(0)" ::: "memory");   // retires A19 + B19
  __builtin_amdgcn_sched_barrier(0);
  WRITEA(1, A1);                                     // A(19) -> A1
  COMPUTE(A0, B0);                                   // tile 18

  // kt=19
  asm volatile("s_waitcnt lgkmcnt(0)" ::: "memory");
  __builtin_amdgcn_sched_barrier(0);
  __builtin_amdgcn_s_barrier();
  __builtin_amdgcn_sched_barrier(0);
  COMPUTE(A1, B1);                                   // tile 19

  __syncthreads();   // full drain before smem reuse as Ls

  // ---- epilogue: logits -> LDS, column-major stride 65 --------------------
  float* Ls = (float*)smem;            // Ls[col*65 + row], col<248 (64.5 KB)
#pragma unroll
  for (int m = 0; m < 2; ++m)
#pragma unroll
    for (int nf = 0; nf < 4; ++nf) {
      int col = wn * 64 + nf * 16 + l15;
      if (col < N_OUT) {
        int rbase = wm * 32 + m * 16 + (lh << 2);
#pragma unroll
        for (int i = 0; i < 4; ++i) Ls[col * 65 + rbase + i] = acc[m][nf][i];
      }
    }
  __syncthreads();

  // 8 threads per row: part p owns root i=p entirely (u1, level-1, level-2).
  const int p = tid & 7;
  const int r = tid >> 3;              // 0..63
  float* orow = out + (size_t)(row0 + r) * N_OUT;

  float ui = Ls[p * 65 + r] + b_final[p];
  orow[p] = ui;

  // level-1: softmax over 6, then u2 = p1 * u1
  float lg[6];
  float mx = -1e30f;
#pragma unroll
  for (int c = 0; c < 6; ++c) {
    lg[c] = Ls[(8 + p * 6 + c) * 65 + r] + ui * wu1[p * 6 + c] + b1[p * 6 + c];
    mx = fmaxf(mx, lg[c]);
  }
  float s = 0.0f;
#pragma unroll
  for (int c = 0; c < 6; ++c) { lg[c] = __expf(lg[c] - mx); s += lg[c]; }
  float sc = ui / s;
  float u2v[6];
#pragma unroll
  for (int c = 0; c < 6; ++c) {
    u2v[c] = lg[c] * sc;
    orow[8 + p * 6 + c] = u2v[c];
  }

  // level-2: 6 groups of 4, u3 = p2 * u2
#pragma unroll
  for (int j = 0; j < 6; ++j) {
    int g = p * 6 + j;
    float ug = u2v[j];
    float l2[4];
    float m2 = -1e30f;
#pragma unroll
    for (int c = 0; c < 4; ++c) {
      l2[c] = Ls[(56 + g * 4 + c) * 65 + r] + ug * wu2[g * 4 + c] + b2[g * 4 + c];
      m2 = fmaxf(m2, l2[c]);
    }
    float s2 = 0.0f;
#pragma unroll
    for (int c = 0; c < 4; ++c) { l2[c] = __expf(l2[c] - m2); s2 += l2[c]; }
    float sc2 = ug / s2;
    f32x4 o;
#pragma unroll
    for (int c = 0; c < 4; ++c) o[c] = l2[c] * sc2;
    *(f32x4*)(orow + 56 + g * 4) = o;
  }
#undef STAGEB
#undef LOADA
#undef WRITEA
#undef COMPUTE
#undef ITER
}

// ---------------------------------------------------------------------------
extern "C" void kernel_launch(void* const* d_in, const int* in_sizes, int n_in,
                              void* d_out, int out_size, void* d_ws, size_t ws_size,
                              hipStream_t stream) {
  const float* x   = (const float*)d_in[0];
  const float* Wf  = (const float*)d_in[1];
  const float* bf  = (const float*)d_in[2];
  const float* Wp1 = (const float*)d_in[3];
  const float* wu1 = (const float*)d_in[4];
  const float* b1  = (const float*)d_in[5];
  const float* Wp2 = (const float*)d_in[6];
  const float* wu2 = (const float*)d_in[7];
  const float* b2  = (const float*)d_in[8];
  float* out = (float*)d_out;
  unsigned short* Wb = (unsigned short*)d_ws;   // 655,360 B packed bf16 weights

  pack_w_kernel<<<160, 256, 0, stream>>>(Wf, Wp1, Wp2, Wb);
  tree_head_kernel<<<16384 / BM, 512, 0, stream>>>(x, Wb, bf, wu1, b1, wu2, b2, out);
}